// Round 9
// baseline (17.084 us; speedup 1.0000x reference)
//
#include <hip/hip_runtime.h>
#include <math.h>

// DynOT: Sinkhorn on 64x6, linear domain, one wave, lane i = row i.
// t-space iteration:  t = rcp(Mh r),  r = rcp(Mta^T t)
// where Mh = M*diag(b^2), Mta = diag(a)*M*diag(b); v = a.*t, u = b^2 .* r.
// Column sums via DPP butterfly + gfx950 permlane swaps. No exp/log in loop.
// R9: ROLLED fixed-trip loop (R8's full unroll paid ~0.8us cold I-fetch at
// idle DVFS clock; rolled loop re-executes ~50 hot insts, SALU loop overhead
// hides under the VALU chain). 14 iters (anchors: absmax(16)=1.9e-6,
// absmax(15)=0.0, contraction ~8x/iter => absmax(14)~1e-5, 25x margin).
// Epilogue: recompute t-half; P row sums = a_i exactly => skip global
// normalization (matches reference to ~1e-8; R8 measured absmax 0.0).

constexpr int B = 6;
constexpr float INV_EPS = 50.0f; // 1 / 0.02
constexpr int FIXED_ITERS = 14;

typedef float v2f __attribute__((ext_vector_type(2)));
typedef int v2i __attribute__((ext_vector_type(2)));

template <int CTRL>
__device__ __forceinline__ float dpp_mov(float v) {
    return __builtin_bit_cast(float,
        __builtin_amdgcn_update_dpp(0, __builtin_bit_cast(int, v), CTRL, 0xF, 0xF, true));
}

// x += shuffle(x); old=0 + bound_ctrl lets GCNDPPCombine fuse into v_add_f32_dpp.
template <int CTRL>
__device__ __forceinline__ v2f bfly_dpp(v2f x) {
    v2f y;
    y.x = dpp_mov<CTRL>(x.x);
    y.y = dpp_mov<CTRL>(x.y);
    return x + y;
}

// xor16 / xor32 exchange via gfx950 permlane swaps; s_nop 1 covers the
// VALU-write -> permlane-read hazard (asm body is opaque to the scheduler).
__device__ __forceinline__ v2f bfly_swap16(v2f x) {
    float a0 = x.x, b0 = x.x, a1 = x.y, b1 = x.y;
    asm volatile("s_nop 1\n\t"
                 "v_permlane16_swap_b32 %0, %1\n\t"
                 "v_permlane16_swap_b32 %2, %3"
                 : "+v"(a0), "+v"(b0), "+v"(a1), "+v"(b1));
    v2f s, t;
    s.x = a0; s.y = a1;
    t.x = b0; t.y = b1;
    return s + t;
}
__device__ __forceinline__ v2f bfly_swap32(v2f x) {
    float a0 = x.x, b0 = x.x, a1 = x.y, b1 = x.y;
    asm volatile("s_nop 1\n\t"
                 "v_permlane32_swap_b32 %0, %1\n\t"
                 "v_permlane32_swap_b32 %2, %3"
                 : "+v"(a0), "+v"(b0), "+v"(a1), "+v"(b1));
    v2f s, t;
    s.x = a0; s.y = a1;
    t.x = b0; t.y = b1;
    return s + t;
}

__global__ __launch_bounds__(64) void dynot_sinkhorn_kernel(
    const float* __restrict__ trH, const float* __restrict__ wmax,
    const float* __restrict__ a, const float* __restrict__ theta,
    const float* __restrict__ phi, const int* __restrict__ bits,
    float* __restrict__ out)
{
    const int i = threadIdx.x; // row index, one wave of 64

    const float trH_i = trH[i];
    const float wmax_i = wmax[i];
    const float a_i = a[i];

    // theta row: 24B per lane, 8B-aligned -> three v2f loads; phi/bits likewise
    const v2f* th2 = (const v2f*)(theta + i * B);
    v2f th[3];
#pragma unroll
    for (int k = 0; k < 3; ++k) th[k] = th2[k];
    const v2f* phi2 = (const v2f*)phi;
    v2f phv[3];
#pragma unroll
    for (int k = 0; k < 3; ++k) phv[k] = phi2[k];
    const v2i* bits2 = (const v2i*)bits;
    v2i btv[3];
#pragma unroll
    for (int k = 0; k < 3; ++k) btv[k] = bits2[k];

    // b = softmax(phi). |phi| <= ~0.05 -> no max-subtraction needed.
    float eb[B];
#pragma unroll
    for (int k = 0; k < 3; ++k) {
        eb[2 * k]     = __expf(phv[k].x);
        eb[2 * k + 1] = __expf(phv[k].y);
    }
    float sb = ((eb[0] + eb[1]) + (eb[2] + eb[3])) + (eb[4] + eb[5]);
    float isb = __builtin_amdgcn_rcpf(sb);
    float bb[B];
#pragma unroll
    for (int j = 0; j < B; ++j) bb[j] = eb[j] * isb;

    // M[i][j] = exp((theta - C)/eps), C = 0.5*trH*(delta^2/12)
    // Mta = a*M*b (column-sum side), Mh = M*b^2 (row-dot side + epilogue)
    v2f Mta2[3], Mh2[3], r2[3];
#pragma unroll
    for (int k = 0; k < 3; ++k) {
#pragma unroll
        for (int h = 0; h < 2; ++h) {
            int j = 2 * k + h;
            int bj = (h == 0) ? btv[k].x : btv[k].y;
            float denom = (float)((1 << bj) - 1);
            float delta = 2.0f * wmax_i * __builtin_amdgcn_rcpf(denom);
            float C = 0.5f * trH_i * (delta * delta * (1.0f / 12.0f));
            float thv = (h == 0) ? th[k].x : th[k].y;
            float M = __expf((thv - C) * INV_EPS);
            float Mb = M * bb[j];
            float r0 = __builtin_amdgcn_rcpf(bb[j] * bb[j]); // u=1 => r = 1/b^2
            if (h == 0) {
                Mta2[k].x = Mb * a_i;
                Mh2[k].x  = Mb * bb[j];
                r2[k].x   = r0;
            } else {
                Mta2[k].y = Mb * a_i;
                Mh2[k].y  = Mb * bb[j];
                r2[k].y   = r0;
            }
        }
    }

    float t = 0.0f;

    auto t_half = [&]() {
        // t_i = rcp( sum_j Mh_ij r_j )
        v2f q0 = Mh2[0] * r2[0];
        v2f q1 = Mh2[1] * r2[1];
        v2f q2 = Mh2[2] * r2[2];
        v2f s2 = (q0 + q1) + q2;
        float s = s2.x + s2.y;
        t = __builtin_amdgcn_rcpf(s);
    };

    // Fixed trip count, ROLLED: small hot loop, scalar loop overhead hides
    // under the VALU dependency chain.
#pragma unroll 1
    for (int it = 0; it < FIXED_ITERS; ++it) {
        t_half();
        // r_j = rcp( sum_i Mta_ij t_i )   (butterfly column sums)
        v2f tt; tt.x = t; tt.y = t;
#pragma unroll
        for (int k = 0; k < 3; ++k) {
            v2f w = Mta2[k] * tt;
            w = bfly_dpp<0xB1>(w);
            w = bfly_dpp<0x4E>(w);
            w = bfly_dpp<0x141>(w);
            w = bfly_dpp<0x140>(w);
            w = bfly_swap16(w);
            w = bfly_swap32(w);
            r2[k].x = __builtin_amdgcn_rcpf(w.x);
            r2[k].y = __builtin_amdgcn_rcpf(w.y);
        }
    }

    // Consistent-phase final t: row sums of P become a_i * rcp(s) * s = a_i
    // (+-1ulp); sum(P) = sum(a) = 1 +- 3e-7, so the reference's global
    // P/(sum P) normalization is a no-op within ~1e-8 (R8: absmax 0.0).
    t_half();

    float v = a_i * t;
    v2f* out2 = (v2f*)(out + i * B); // 24B/lane, 8B-aligned
#pragma unroll
    for (int k = 0; k < 3; ++k) {
        v2f pp = Mh2[k] * r2[k];
        v2f o;
        o.x = pp.x * v;
        o.y = pp.y * v;
        out2[k] = o;
    }
}

extern "C" void kernel_launch(void* const* d_in, const int* in_sizes, int n_in,
                              void* d_out, int out_size, void* d_ws, size_t ws_size,
                              hipStream_t stream) {
    const float* trH   = (const float*)d_in[0];
    const float* wmaxp = (const float*)d_in[1];
    const float* a     = (const float*)d_in[2];
    const float* theta = (const float*)d_in[3];
    const float* phi   = (const float*)d_in[4];
    const int*   bits  = (const int*)d_in[5];
    float* out = (float*)d_out;

    hipLaunchKernelGGL(dynot_sinkhorn_kernel, dim3(1), dim3(64), 0, stream,
                       trH, wmaxp, a, theta, phi, bits, out);
}

// Round 10
// 9.274 us; speedup vs baseline: 1.8422x; 1.8422x over previous
//
#include <hip/hip_runtime.h>
#include <math.h>

// DynOT: Sinkhorn on 64x6, linear domain, one wave, lane i = row i.
// t-space iteration:  t = rcp(Mh r),  r = rcp(Mta^T t)
// where Mh = M*diag(b^2), Mta = diag(a)*M*diag(b); v = a.*t, u = b^2 .* r.
// Column sums via DPP butterfly + gfx950 permlane swaps. No exp/log in loop.
// R10: RE-ANCHOR. Revert to the twice-proven R6/R7 adaptive rolled loop
// (pair-granularity exit, tol 2^-9) after two consecutive mispredictions
// (R8 unrolled-15: 10.2us, R9 rolled-fixed-14: 17.1us). Keep only the
// correctness-proven cheap epilogue (R8: absmax 0.0; P row sums = a_i
// exactly, sum(P)=1+-3e-7 => skip global normalize) and vectorized loads.

constexpr int B = 6;
constexpr float INV_EPS = 50.0f;          // 1 / 0.02
constexpr float EXIT_TOL = 1.953125e-03f; // 2^-9
constexpr int MAX_PAIRS = 100;            // 200 iterations cap

typedef float v2f __attribute__((ext_vector_type(2)));
typedef int v2i __attribute__((ext_vector_type(2)));

template <int CTRL>
__device__ __forceinline__ float dpp_mov(float v) {
    return __builtin_bit_cast(float,
        __builtin_amdgcn_update_dpp(0, __builtin_bit_cast(int, v), CTRL, 0xF, 0xF, true));
}

// x += shuffle(x); old=0 + bound_ctrl lets GCNDPPCombine fuse into v_add_f32_dpp.
template <int CTRL>
__device__ __forceinline__ v2f bfly_dpp(v2f x) {
    v2f y;
    y.x = dpp_mov<CTRL>(x.x);
    y.y = dpp_mov<CTRL>(x.y);
    return x + y;
}

// xor16 / xor32 exchange via gfx950 permlane swaps; s_nop 1 covers the
// VALU-write -> permlane-read hazard (asm body is opaque to the scheduler).
__device__ __forceinline__ v2f bfly_swap16(v2f x) {
    float a0 = x.x, b0 = x.x, a1 = x.y, b1 = x.y;
    asm volatile("s_nop 1\n\t"
                 "v_permlane16_swap_b32 %0, %1\n\t"
                 "v_permlane16_swap_b32 %2, %3"
                 : "+v"(a0), "+v"(b0), "+v"(a1), "+v"(b1));
    v2f s, t;
    s.x = a0; s.y = a1;
    t.x = b0; t.y = b1;
    return s + t;
}
__device__ __forceinline__ v2f bfly_swap32(v2f x) {
    float a0 = x.x, b0 = x.x, a1 = x.y, b1 = x.y;
    asm volatile("s_nop 1\n\t"
                 "v_permlane32_swap_b32 %0, %1\n\t"
                 "v_permlane32_swap_b32 %2, %3"
                 : "+v"(a0), "+v"(b0), "+v"(a1), "+v"(b1));
    v2f s, t;
    s.x = a0; s.y = a1;
    t.x = b0; t.y = b1;
    return s + t;
}

__global__ __launch_bounds__(64) void dynot_sinkhorn_kernel(
    const float* __restrict__ trH, const float* __restrict__ wmax,
    const float* __restrict__ a, const float* __restrict__ theta,
    const float* __restrict__ phi, const int* __restrict__ bits,
    float* __restrict__ out)
{
    const int i = threadIdx.x; // row index, one wave of 64

    const float trH_i = trH[i];
    const float wmax_i = wmax[i];
    const float a_i = a[i];

    // theta row: 24B per lane, 8B-aligned -> three v2f loads; phi/bits likewise
    const v2f* th2 = (const v2f*)(theta + i * B);
    v2f th[3];
#pragma unroll
    for (int k = 0; k < 3; ++k) th[k] = th2[k];
    const v2f* phi2 = (const v2f*)phi;
    v2f phv[3];
#pragma unroll
    for (int k = 0; k < 3; ++k) phv[k] = phi2[k];
    const v2i* bits2 = (const v2i*)bits;
    v2i btv[3];
#pragma unroll
    for (int k = 0; k < 3; ++k) btv[k] = bits2[k];

    // b = softmax(phi). |phi| <= ~0.05 -> no max-subtraction needed.
    float eb[B];
#pragma unroll
    for (int k = 0; k < 3; ++k) {
        eb[2 * k]     = __expf(phv[k].x);
        eb[2 * k + 1] = __expf(phv[k].y);
    }
    float sb = ((eb[0] + eb[1]) + (eb[2] + eb[3])) + (eb[4] + eb[5]);
    float isb = __builtin_amdgcn_rcpf(sb);
    float bb[B];
#pragma unroll
    for (int j = 0; j < B; ++j) bb[j] = eb[j] * isb;

    // M[i][j] = exp((theta - C)/eps), C = 0.5*trH*(delta^2/12)
    // Mta = a*M*b (column-sum side), Mh = M*b^2 (row-dot side + epilogue)
    v2f Mta2[3], Mh2[3], r2[3];
#pragma unroll
    for (int k = 0; k < 3; ++k) {
#pragma unroll
        for (int h = 0; h < 2; ++h) {
            int j = 2 * k + h;
            int bj = (h == 0) ? btv[k].x : btv[k].y;
            float denom = (float)((1 << bj) - 1);
            float delta = 2.0f * wmax_i * __builtin_amdgcn_rcpf(denom);
            float C = 0.5f * trH_i * (delta * delta * (1.0f / 12.0f));
            float thv = (h == 0) ? th[k].x : th[k].y;
            float M = __expf((thv - C) * INV_EPS);
            float Mb = M * bb[j];
            float r0 = __builtin_amdgcn_rcpf(bb[j] * bb[j]); // u=1 => r = 1/b^2
            if (h == 0) {
                Mta2[k].x = Mb * a_i;
                Mh2[k].x  = Mb * bb[j];
                r2[k].x   = r0;
            } else {
                Mta2[k].y = Mb * a_i;
                Mh2[k].y  = Mb * bb[j];
                r2[k].y   = r0;
            }
        }
    }

    float t = 0.0f;

    auto t_half = [&]() {
        // t_i = rcp( sum_j Mh_ij r_j )
        v2f q0 = Mh2[0] * r2[0];
        v2f q1 = Mh2[1] * r2[1];
        v2f q2 = Mh2[2] * r2[2];
        v2f s2 = (q0 + q1) + q2;
        float s = s2.x + s2.y;
        t = __builtin_amdgcn_rcpf(s);
    };

    auto body = [&]() {
        t_half();
        // r_j = rcp( sum_i Mta_ij t_i )   (butterfly column sums)
        v2f tt; tt.x = t; tt.y = t;
#pragma unroll
        for (int k = 0; k < 3; ++k) {
            v2f w = Mta2[k] * tt;
            w = bfly_dpp<0xB1>(w);
            w = bfly_dpp<0x4E>(w);
            w = bfly_dpp<0x141>(w);
            w = bfly_dpp<0x140>(w);
            w = bfly_swap16(w);
            w = bfly_swap32(w);
            r2[k].x = __builtin_amdgcn_rcpf(w.x);
            r2[k].y = __builtin_amdgcn_rcpf(w.y);
        }
    };

    // Pair-granularity exit: |t - t_prev_pair| <= t * 2^-9 on all lanes.
    // (No bitwise backstop: worst case is the 200-iter cap, still correct.)
    float t_prev = __builtin_bit_cast(float, 0x7FC00001u); // never matches

#pragma unroll 1
    for (int p = 0; p < MAX_PAIRS; ++p) {
        body();
        body();
        float d = fabsf(t - t_prev);
        if (__all(d <= t * EXIT_TOL)) break;
        t_prev = t;
    }

    // Consistent-phase final t: row sums of P become a_i * rcp(s) * s = a_i
    // (+-1ulp); sum(P) = sum(a) = 1 +- 3e-7, so the reference's global
    // P/(sum P) normalization is a no-op within ~1e-8 (R8: absmax 0.0).
    t_half();

    float v = a_i * t;
    v2f* out2 = (v2f*)(out + i * B); // 24B/lane, 8B-aligned
#pragma unroll
    for (int k = 0; k < 3; ++k) {
        v2f pp = Mh2[k] * r2[k];
        v2f o;
        o.x = pp.x * v;
        o.y = pp.y * v;
        out2[k] = o;
    }
}

extern "C" void kernel_launch(void* const* d_in, const int* in_sizes, int n_in,
                              void* d_out, int out_size, void* d_ws, size_t ws_size,
                              hipStream_t stream) {
    const float* trH   = (const float*)d_in[0];
    const float* wmaxp = (const float*)d_in[1];
    const float* a     = (const float*)d_in[2];
    const float* theta = (const float*)d_in[3];
    const float* phi   = (const float*)d_in[4];
    const int*   bits  = (const int*)d_in[5];
    float* out = (float*)d_out;

    hipLaunchKernelGGL(dynot_sinkhorn_kernel, dim3(1), dim3(64), 0, stream,
                       trH, wmaxp, a, theta, phi, bits, out);
}